// Round 11
// baseline (540.686 us; speedup 1.0000x reference)
//
#include <hip/hip_runtime.h>

// Graphormer encoder — bf16 MFMA GEMMs, fp32 residual path. Multi-dispatch.
// R19: attention + O-projection + residual fused (layers 0..2). Grid
// 64 graphs x 4 col-slices; each block computes its graph's full attention
// (8 heads, o tile in LDS) then o @ Wo[:,slice] with K=512 in-block; epilogue
// adds bias + residual via plain RMW (block owns its output region). Removes
// per-layer: 1 dispatch, 4MB o round-trip, 16MB Wo split-K atomics.
// Everything else = R18 (R16-equivalent, 451.7us).

#define NG   64
#define NP   31
#define NORI 1984
#define NT   2048
#define DIM  512
#define NHD  8
#define DKH  64
#define FFD  2048
#define NLAY 4
#define NFEA 32

typedef __attribute__((ext_vector_type(8))) short short8;
typedef __attribute__((ext_vector_type(4))) float floatx4;

__device__ __forceinline__ unsigned short f2bf(float f) {
    union { float f; unsigned u; } v; v.f = f;
    unsigned r = v.u + 0x7fffu + ((v.u >> 16) & 1u);
    return (unsigned short)(r >> 16);
}
__device__ __forceinline__ float bf2f(unsigned short u) {
    union { unsigned u; float f; } v; v.u = ((unsigned)u) << 16;
    return v.f;
}

// ---------------------------------------------------------------- merged prep (1 dispatch)
__global__ __launch_bounds__(256) void prep_all(
    const float* __restrict__ x, const int* __restrict__ degrees,
    const float* __restrict__ init_W, const float* __restrict__ init_b,
    const float* __restrict__ cent_emb, float* __restrict__ h,
    const int* __restrict__ sp, const float* __restrict__ db,
    const float* __restrict__ virt_bias, float* __restrict__ Bg,
    const float* __restrict__ Wq, const float* __restrict__ Wk,
    const float* __restrict__ Wv, const float* __restrict__ bq,
    const float* __restrict__ bk, const float* __restrict__ bv,
    unsigned short* __restrict__ Wqkv_t, float* __restrict__ bqkv,
    const float* __restrict__ Wo, const float* __restrict__ W1,
    const float* __restrict__ W2, unsigned short* __restrict__ Wo_t,
    unsigned short* __restrict__ W1_t, unsigned short* __restrict__ W2_t)
{
    __shared__ float tl[32][33];
    int u = blockIdx.x;
    int tid = threadIdx.x;

    if (u < 2112) {                       // ---- init_h + build_B
        int n = u;
        if (n >= NT) {                    // B-build: one block per graph
            int g = n - NT;
            float vb = virt_bias[0];
            for (int e = tid; e < 1024; e += 256) {
                int i = e >> 5, j = e & 31;
                float v;
                if (i == j) v = db[0];
                else if (i < NP && j < NP) {
                    int s = sp[(size_t)(g * NP + i) * NORI + g * NP + j];
                    v = db[s < 100 ? s : 100];
                } else v = vb;
                Bg[(size_t)g * 1024 + e] = v;
            }
            return;
        }
        float* xs = &tl[0][0];
        if (n < NORI && tid < NFEA) xs[tid] = x[(size_t)n * NFEA + tid];
        __syncthreads();
        int deg = degrees[n]; if (deg > 100) deg = 100;
        for (int d = tid; d < DIM; d += 256) {
            float v = cent_emb[(size_t)deg * DIM + d];
            if (n < NORI) {
                float acc = init_b[d];
                #pragma unroll
                for (int k = 0; k < NFEA; ++k) acc += xs[k] * init_W[(size_t)k * DIM + d];
                v += acc;
            }
            h[(size_t)n * DIM + d] = v;
        }
        return;
    }
    if (u < 5208) {                       // ---- QKV weight transpose + bias
        int tile = u - 2112;
        if (tile >= 3072) {
            int idx = (tile - 3072) * 256 + tid;
            if (idx < NLAY * 1536) {
                int l = idx / 1536, c = idx % 1536;
                int which = c >> 9, cc = c & 511;
                const float* b = (which == 0) ? bq : (which == 1) ? bk : bv;
                bqkv[idx] = b[(size_t)l * 512 + cc];
            }
            return;
        }
        int slice = tile >> 5;
        int tloc = tile & 31;
        int dt = tloc >> 1, kt = tloc & 1;
        int l = slice / 24; int rem = slice % 24; int which = rem >> 3; int hh = rem & 7;
        const float* W = (which == 0) ? Wq : (which == 1) ? Wk : Wv;
        const float* in = W + (size_t)(l * 8 + hh) * DIM * DKH;
        int tr = tid >> 5, tc = tid & 31;
        #pragma unroll
        for (int pp = 0; pp < 4; ++pp)
            tl[tr + pp * 8][tc] = in[(size_t)(dt * 32 + tr + pp * 8) * DKH + kt * 32 + tc];
        __syncthreads();
        unsigned short* out = Wqkv_t +
            ((size_t)l * 1536 + which * 512 + hh * 64 + kt * 32) * DIM + dt * 32;
        #pragma unroll
        for (int pp = 0; pp < 4; ++pp)
            out[(size_t)(tr + pp * 8) * DIM + tc] = f2bf(tl[tc][tr + pp * 8]);
        return;
    }
    {                                     // ---- Wo/W1/W2 transpose
        int id = u - 5208;
        const float* in; unsigned short* outp; int R, C, l, rt, ct;
        if (id < 1024) {
            l = id >> 8; int t = id & 255; rt = t >> 4; ct = t & 15;
            in = Wo; outp = Wo_t; R = 512; C = 512;
        } else if (id < 5120) {
            int t2 = id - 1024; l = t2 >> 10; int t = t2 & 1023; rt = t >> 6; ct = t & 63;
            in = W1; outp = W1_t; R = 512; C = 2048;
        } else {
            int t2 = id - 5120; l = t2 >> 10; int t = t2 & 1023; rt = t >> 4; ct = t & 15;
            in = W2; outp = W2_t; R = 2048; C = 512;
        }
        const float* ip = in + (size_t)l * R * C;
        unsigned short* op = outp + (size_t)l * R * C;
        int r0 = rt * 32, c0 = ct * 32;
        int tr = tid >> 5, tc = tid & 31;
        #pragma unroll
        for (int pp = 0; pp < 4; ++pp)
            tl[tr + pp * 8][tc] = ip[(size_t)(r0 + tr + pp * 8) * C + c0 + tc];
        __syncthreads();
        #pragma unroll
        for (int pp = 0; pp < 4; ++pp)
            op[(size_t)(c0 + tr + pp * 8) * R + r0 + tc] = f2bf(tl[tc][tr + pp * 8]);
    }
}

// ---------------------------------------------------------------- layernorm: fp32 in -> bf16 out
__global__ __launch_bounds__(256) void layernorm_bf16(
    const float* __restrict__ in, unsigned short* __restrict__ out, int row0,
    float* __restrict__ fout)
{
    int n = row0 + blockIdx.x;
    int tid = threadIdx.x;
    const float* row = in + (size_t)n * DIM;
    float v0 = row[tid], v1 = row[tid + 256];
    float s = v0 + v1;
    float sq = v0 * v0 + v1 * v1;
    #pragma unroll
    for (int off = 32; off > 0; off >>= 1) {
        s  += __shfl_down(s, off);
        sq += __shfl_down(sq, off);
    }
    __shared__ float red[8];
    int wave = tid >> 6;
    if ((tid & 63) == 0) { red[wave] = s; red[4 + wave] = sq; }
    __syncthreads();
    float ts  = red[0] + red[1] + red[2] + red[3];
    float tsq = red[4] + red[5] + red[6] + red[7];
    float m   = ts * (1.0f / DIM);
    float var = tsq * (1.0f / DIM) - m * m;
    float inv = rsqrtf(var + 1e-5f);
    out[(size_t)n * DIM + tid]       = f2bf((v0 - m) * inv);
    out[(size_t)n * DIM + tid + 256] = f2bf((v1 - m) * inv);
    if (fout) {
        fout[(size_t)(n - row0) * DIM + tid]       = v0;
        fout[(size_t)(n - row0) * DIM + tid + 256] = v1;
    }
}

// ---------------------------------------------------------------- bf16 MFMA GEMM, 64-tile (small M)
template<int SPLITK>
__global__ __launch_bounds__(256) void gemm64(
    const unsigned short* __restrict__ A, const unsigned short* __restrict__ Bt,
    const float* __restrict__ bias, void* __restrict__ out,
    int Nfull, int K, int moff, int flags, int P, int C, int orow)
{
    __shared__ __align__(16) unsigned short Asl[64 * 72];
    __shared__ __align__(16) unsigned short Bsl[64 * 72];
    int id = blockIdx.x;
    int by, bx, bz;
    if (P >= 8) {
        int xcd = id & 7, t = id >> 3, G = P >> 3;
        by = xcd + 8 * (t % G);
        int r2 = t / G;
        bx = r2 % C;
        bz = r2 / C;
    } else {
        by = id % P; int r2 = id / P; bx = r2 % C; bz = r2 / C;
    }
    int tid = threadIdx.x;
    int row0 = moff + by * 64, col0 = bx * 64;
    if ((flags & 4) && col0 < 512 && row0 < NORI) return;
    int kslice = K / SPLITK;
    int kbeg = bz * kslice;
    int wave = tid >> 6, lane = tid & 63;
    int quad = lane >> 4, m16 = lane & 15;
    int mw = (wave >> 1) * 32, nw = (wave & 1) * 32;
    floatx4 acc[2][2] = {};
    for (int k0 = kbeg; k0 < kbeg + kslice; k0 += 64) {
        #pragma unroll
        for (int p = 0; p < 2; ++p) {
            int idx = (p * 256 + tid) * 8;
            int r = idx >> 6, kk = idx & 63;
            *(float4*)(Asl + r * 72 + kk) =
                *(const float4*)(A + (size_t)(row0 + r) * K + k0 + kk);
            *(float4*)(Bsl + r * 72 + kk) =
                *(const float4*)(Bt + (size_t)(col0 + r) * K + k0 + kk);
        }
        __syncthreads();
        #pragma unroll
        for (int ks = 0; ks < 64; ks += 32) {
            short8 a[2], b[2];
            #pragma unroll
            for (int mi = 0; mi < 2; ++mi)
                a[mi] = *(const short8*)(Asl + (mw + mi * 16 + m16) * 72 + ks + quad * 8);
            #pragma unroll
            for (int ni = 0; ni < 2; ++ni)
                b[ni] = *(const short8*)(Bsl + (nw + ni * 16 + m16) * 72 + ks + quad * 8);
            #pragma unroll
            for (int mi = 0; mi < 2; ++mi)
                #pragma unroll
                for (int ni = 0; ni < 2; ++ni)
                    acc[mi][ni] = __builtin_amdgcn_mfma_f32_16x16x32_bf16(
                        a[mi], b[ni], acc[mi][ni], 0, 0, 0);
        }
        __syncthreads();
    }
    if (SPLITK == 1) {
        int do_relu = flags & 1, out_bf = flags & 2;
        #pragma unroll
        for (int mi = 0; mi < 2; ++mi) {
            #pragma unroll
            for (int ni = 0; ni < 2; ++ni) {
                int col = col0 + nw + ni * 16 + m16;
                float bval = bias[col];
                #pragma unroll
                for (int rr = 0; rr < 4; ++rr) {
                    int row = row0 + mw + mi * 16 + quad * 4 + rr;
                    float v = acc[mi][ni][rr] + bval;
                    if (do_relu) v = fmaxf(v, 0.0f);
                    if (out_bf) ((unsigned short*)out)[(size_t)(row - orow) * Nfull + col] = f2bf(v);
                    else        ((float*)out)[(size_t)(row - orow) * Nfull + col] = v;
                }
            }
        }
    } else {
        float* o = (float*)out;
        float bscale = (bz == 0) ? 1.0f : 0.0f;
        #pragma unroll
        for (int mi = 0; mi < 2; ++mi) {
            #pragma unroll
            for (int ni = 0; ni < 2; ++ni) {
                int col = col0 + nw + ni * 16 + m16;
                float bval = bias[col] * bscale;
                #pragma unroll
                for (int rr = 0; rr < 4; ++rr) {
                    int row = row0 + mw + mi * 16 + quad * 4 + rr;
                    atomicAdd(&o[(size_t)(row - orow) * Nfull + col],
                              acc[mi][ni][rr] + bval);
                }
            }
        }
    }
}

// ---------------------------------------------------------------- bf16 MFMA GEMM, 128-tile
// 2-phase: double-buffered LDS; next-tile DMA before compute; counted vmcnt.
__device__ __forceinline__ void stage128(
    const unsigned short* __restrict__ Abase, const unsigned short* __restrict__ Bbase,
    int K, int k0, unsigned short* Asl, unsigned short* Bsl,
    int wave, int lane, int lr, int scol)
{
    #pragma unroll
    for (int p = 0; p < 4; ++p) {
        int chunk = wave * 4 + p;
        int r = chunk * 8 + lr;
        __builtin_amdgcn_global_load_lds(
            (const __attribute__((address_space(1))) unsigned int*)
                (Abase + (size_t)r * K + k0 + scol),
            (__attribute__((address_space(3))) unsigned int*)
                (Asl + chunk * 512 + lane * 8), 16, 0, 0);
        __builtin_amdgcn_global_load_lds(
            (const __attribute__((address_space(1))) unsigned int*)
                (Bbase + (size_t)r * K + k0 + scol),
            (__attribute__((address_space(3))) unsigned int*)
                (Bsl + chunk * 512 + lane * 8), 16, 0, 0);
    }
}

template<int SPLITK>
__global__ __launch_bounds__(256) void gemm128(
    const unsigned short* __restrict__ A, const unsigned short* __restrict__ Bt,
    const float* __restrict__ bias, void* __restrict__ out,
    int Nfull, int K, int flags, int P, int C)
{
    __shared__ __align__(16) unsigned short Asl[2][128 * 64];
    __shared__ __align__(16) unsigned short Bsl[2][128 * 64];
    int id = blockIdx.x;
    int xcd = id & 7, t = id >> 3, Gp = P >> 3;
    int by = xcd + 8 * (t % Gp);
    int r2 = t / Gp;
    int bx = r2 % C;
    int bz = r2 / C;
    int tid = threadIdx.x;
    int row0 = by * 128, col0 = bx * 128;
    if ((flags & 4) && col0 < 512 && row0 + 128 <= NORI) return;   // Q only for virt panel
    int kslice = K / SPLITK;
    int kbeg = bz * kslice;
    int nk = kslice >> 6;
    int wave = tid >> 6, lane = tid & 63;
    int quad = lane >> 4, m16 = lane & 15;
    int mw = (wave >> 1) * 64, nw = (wave & 1) * 64;
    int lr = lane >> 3;
    int scol = ((lane & 7) ^ lr) << 3;
    int rdswz = (m16 & 7) << 4;
    const unsigned short* Abase = A + (size_t)row0 * K;
    const unsigned short* Bbase = Bt + (size_t)col0 * K;
    floatx4 acc[4][4] = {};

    stage128(Abase, Bbase, K, kbeg, Asl[0], Bsl[0], wave, lane, lr, scol);
    int cur = 0;
    for (int i = 0; i < nk; ++i) {
        if (i + 1 < nk) {
            stage128(Abase, Bbase, K, kbeg + (i + 1) * 64,
                     Asl[cur ^ 1], Bsl[cur ^ 1], wave, lane, lr, scol);
            asm volatile("s_waitcnt vmcnt(8)" ::: "memory");
        } else {
            asm volatile("s_waitcnt vmcnt(0)" ::: "memory");
        }
        __builtin_amdgcn_s_barrier();
        const char* Ac = (const char*)Asl[cur];
        const char* Bc = (const char*)Bsl[cur];
        #pragma unroll
        for (int ks = 0; ks < 64; ks += 32) {
            short8 a[4], b[4];
            int cb = (ks + quad * 8) * 2;
            #pragma unroll
            for (int mi = 0; mi < 4; ++mi)
                a[mi] = *(const short8*)(Ac + (mw + mi * 16 + m16) * 128 + (cb ^ rdswz));
            #pragma unroll
            for (int ni = 0; ni < 4; ++ni)
                b[ni] = *(const short8*)(Bc + (nw + ni * 16 + m16) * 128 + (cb ^ rdswz));
            #pragma unroll
            for (int mi = 0; mi < 4; ++mi)
                #pragma unroll
                for (int ni = 0; ni < 4; ++ni)
                    acc[mi][ni] = __builtin_amdgcn_mfma_f32_16x16x32_bf16(
                        a[mi], b[ni], acc[mi][ni], 0, 0, 0);
        }
        __builtin_amdgcn_s_barrier();
        asm volatile("" ::: "memory");
        cur ^= 1;
    }
    if (SPLITK == 1) {
        int do_relu = flags & 1, out_bf = flags & 2;
        #pragma unroll
        for (int mi = 0; mi < 4; ++mi) {
            #pragma unroll
            for (int ni = 0; ni < 4; ++ni) {
                int col = col0 + nw + ni * 16 + m16;
                float bval = bias[col];
                #pragma unroll
                for (int rr = 0; rr < 4; ++rr) {
                    int row = row0 + mw + mi * 16 + quad * 4 + rr;
                    float v = acc[mi][ni][rr] + bval;
                    if (do_relu) v = fmaxf(v, 0.0f);
                    if (out_bf) ((unsigned short*)out)[(size_t)row * Nfull + col] = f2bf(v);
                    else        ((float*)out)[(size_t)row * Nfull + col] = v;
                }
            }
        }
    } else {
        float* o = (float*)out;
        float bscale = (bz == 0) ? 1.0f : 0.0f;
        #pragma unroll
        for (int mi = 0; mi < 4; ++mi) {
            #pragma unroll
            for (int ni = 0; ni < 4; ++ni) {
                int col = col0 + nw + ni * 16 + m16;
                float bval = bias[col] * bscale;
                #pragma unroll
                for (int rr = 0; rr < 4; ++rr) {
                    int row = row0 + mw + mi * 16 + quad * 4 + rr;
                    atomicAdd(&o[(size_t)row * Nfull + col], acc[mi][ni][rr] + bval);
                }
            }
        }
    }
}

// ---------------------------------------------------------------- fused attention + O-proj + residual
// Grid: 64 graphs x 4 col-slices. Phase 1: full attention for graph g (8 heads)
// into o_lds (bf16, [32][520]). Phase 2: o_lds @ Wo[:, cs*128..+128] (K=512,
// B staged via global_load_lds into union over phase-1 scratch), epilogue adds
// bo + h residual via plain RMW (block owns its (graph, slice) region).
__global__ __launch_bounds__(256) void attn_wo(
    const unsigned short* __restrict__ qkv, const float* __restrict__ Bg,
    const unsigned short* __restrict__ Wo_t, const float* __restrict__ bo,
    float* __restrict__ h)
{
    __shared__ __align__(16) unsigned short o_lds[32][520];
    __shared__ __align__(16) union U {
        struct { float Qs[32][65], Ks[32][65], Vs[32][65], S[32][33]; } p1;
        unsigned short Bsl[128 * 64];
    } u;
    int id = blockIdx.x;
    int g = id >> 2, cs = id & 3;
    int tid = threadIdx.x;
    int i = tid >> 3;
    int c0q = (tid & 7) * 8;
    int gni = (i < NP) ? g * NP + i : NORI + g;

    // ---- phase 1: attention, 8 heads -> o_lds
    for (int hh = 0; hh < NHD; ++hh) {
        const unsigned short* base = qkv + (size_t)gni * 1536 + hh * DKH;
        short8 qv = *(const short8*)(base + c0q);
        short8 kv = *(const short8*)(base + 512 + c0q);
        short8 vv = *(const short8*)(base + 1024 + c0q);
        #pragma unroll
        for (int j = 0; j < 8; ++j) {
            u.p1.Qs[i][c0q + j] = bf2f((unsigned short)qv[j]);
            u.p1.Ks[i][c0q + j] = bf2f((unsigned short)kv[j]);
            u.p1.Vs[i][c0q + j] = bf2f((unsigned short)vv[j]);
        }
        __syncthreads();
        #pragma unroll
        for (int e = 0; e < 4; ++e) {
            int idx = tid + e * 256;
            int si = idx >> 5, sj = idx & 31;
            float dot = 0.0f;
            #pragma unroll
            for (int k = 0; k < DKH; ++k) dot += u.p1.Qs[si][k] * u.p1.Ks[sj][k];
            u.p1.S[si][sj] = dot * 0.125f + Bg[(size_t)g * 1024 + si * 32 + sj];
        }
        __syncthreads();
        if (tid < 32) {
            float mx = -1e30f;
            #pragma unroll
            for (int j = 0; j < 32; ++j) mx = fmaxf(mx, u.p1.S[tid][j]);
            float sum = 0.0f;
            #pragma unroll
            for (int j = 0; j < 32; ++j) {
                float e = __expf(u.p1.S[tid][j] - mx);
                u.p1.S[tid][j] = e; sum += e;
            }
            float inv = 1.0f / sum;
            #pragma unroll
            for (int j = 0; j < 32; ++j) u.p1.S[tid][j] *= inv;
        }
        __syncthreads();
        #pragma unroll
        for (int cc = 0; cc < 8; ++cc) {
            float acc = 0.0f;
            #pragma unroll
            for (int j = 0; j < 32; ++j) acc += u.p1.S[i][j] * u.p1.Vs[j][c0q + cc];
            o_lds[i][hh * DKH + c0q + cc] = f2bf(acc);
        }
        __syncthreads();        // protects Qs/Ks/Vs/S reuse AND o_lds before phase 2
    }

    // ---- phase 2: o(32x512) @ Wo[:, cs*128..+128] + bo + residual
    int wave = tid >> 6, lane = tid & 63;
    int quad = lane >> 4, m16 = lane & 15;
    int nw = wave * 32;
    int lr = lane >> 3;
    int scol = ((lane & 7) ^ lr) << 3;
    int rdswz = (m16 & 7) << 4;
    int c0 = cs * 128;
    const unsigned short* Bbase = Wo_t + (size_t)c0 * 512;
    floatx4 acc[2][2] = {};
    for (int k0 = 0; k0 < 512; k0 += 64) {
        #pragma unroll
        for (int p = 0; p < 4; ++p) {
            int chunk = wave * 4 + p;
            int r = chunk * 8 + lr;            // col index within 128-slice
            __builtin_amdgcn_global_load_lds(
                (const __attribute__((address_space(1))) unsigned int*)
                    (Bbase + (size_t)r * 512 + k0 + scol),
                (__attribute__((address_space(3))) unsigned int*)
                    (u.Bsl + chunk * 512 + lane * 8), 16, 0, 0);
        }
        __syncthreads();                       // drains vmcnt before reads
        #pragma unroll
        for (int ks = 0; ks < 64; ks += 32) {
            short8 a[2], b[2];
            int cb = (ks + quad * 8) * 2;
            #pragma unroll
            for (int mi = 0; mi < 2; ++mi)
                a[mi] = *(const short8*)(&o_lds[mi * 16 + m16][k0 + ks + quad * 8]);
            #pragma unroll
            for (int ni = 0; ni < 2; ++ni)
                b[ni] = *(const short8*)((const char*)u.Bsl +
                        (nw + ni * 16 + m16) * 128 + (cb ^ rdswz));
            #pragma unroll
            for (int mi = 0; mi < 2; ++mi)
                #pragma unroll
                for (int ni = 0; ni < 2; ++ni)
                    acc[mi][ni] = __builtin_amdgcn_mfma_f32_16x16x32_bf16(
                        a[mi], b[ni], acc[mi][ni], 0, 0, 0);
        }
        __syncthreads();
    }
    #pragma unroll
    for (int mi = 0; mi < 2; ++mi) {
        #pragma unroll
        for (int ni = 0; ni < 2; ++ni) {
            int col = c0 + nw + ni * 16 + m16;
            float bval = bo[col];
            #pragma unroll
            for (int rr = 0; rr < 4; ++rr) {
                int row = mi * 16 + quad * 4 + rr;
                int gn = (row < NP) ? g * NP + row : NORI + g;
                float* hp = &h[(size_t)gn * DIM + col];
                *hp = *hp + acc[mi][ni][rr] + bval;
            }
        }
    }
}

// ---------------------------------------------------------------- last-layer attention
__global__ __launch_bounds__(64) void attention_last(
    const unsigned short* __restrict__ qkv, const float* __restrict__ Bg,
    unsigned short* __restrict__ O)
{
    int g = blockIdx.x >> 3, hh = blockIdx.x & 7;
    __shared__ float Ks[32][65], Vs[32][65];
    __shared__ float Qs[64], P[32];
    int tid = threadIdx.x;
    int j = tid & 31, hf = tid >> 5;
    int gn = (j < NP) ? g * NP + j : NORI + g;
    const unsigned short* kb = qkv + (size_t)gn * 1536 + hh * DKH + 512 + hf * 32;
    #pragma unroll
    for (int c = 0; c < 32; c += 8) {
        short8 k8 = *(const short8*)(kb + c);
        short8 v8 = *(const short8*)(kb + 512 + c);
        #pragma unroll
        for (int t = 0; t < 8; ++t) {
            Ks[j][hf * 32 + c + t] = bf2f((unsigned short)k8[t]);
            Vs[j][hf * 32 + c + t] = bf2f((unsigned short)v8[t]);
        }
    }
    Qs[tid] = bf2f(qkv[(size_t)(NORI + g) * 1536 + hh * DKH + tid]);
    __syncthreads();
    float s;
    if (tid < 32) {
        float dot = 0.0f;
        #pragma unroll
        for (int k = 0; k < 64; ++k) dot += Qs[k] * Ks[tid][k];
        s = dot * 0.125f + Bg[(size_t)g * 1024 + 31 * 32 + tid];
    } else s = -1e30f;
    float mx = s;
    #pragma unroll
    for (int off = 32; off > 0; off >>= 1) mx = fmaxf(mx, __shfl_xor(mx, off));
    float e = (tid < 32) ? __expf(s - mx) : 0.0f;
    float sum = e;
    #pragma unroll
    for (int off = 32; off > 0; off >>= 1) sum += __shfl_xor(sum, off);
    if (tid < 32) P[tid] = e / sum;
    __syncthreads();
    float acc = 0.0f;
    #pragma unroll
    for (int jj = 0; jj < 32; ++jj) acc += P[jj] * Vs[jj][tid];
    O[(size_t)(NORI + g) * DIM + hh * DKH + tid] = f2bf(acc);
}

// ---------------------------------------------------------------- launch
extern "C" void kernel_launch(void* const* d_in, const int* in_sizes, int n_in,
                              void* d_out, int out_size, void* d_ws, size_t ws_size,
                              hipStream_t stream)
{
    const float* x        = (const float*)d_in[0];
    const int*   sp       = (const int*)d_in[1];
    const int*   degrees  = (const int*)d_in[3];
    const float* init_W   = (const float*)d_in[4];
    const float* init_b   = (const float*)d_in[5];
    const float* cent_emb = (const float*)d_in[6];
    const float* db       = (const float*)d_in[7];
    const float* vbias    = (const float*)d_in[8];
    const float* Wq       = (const float*)d_in[9];
    const float* bq       = (const float*)d_in[10];
    const float* Wk       = (const float*)d_in[11];
    const float* bk       = (const float*)d_in[12];
    const float* Wv       = (const float*)d_in[13];
    const float* bv       = (const float*)d_in[14];
    const float* Wo       = (const float*)d_in[15];
    const float* bo       = (const float*)d_in[16];
    const float* W1       = (const float*)d_in[17];
    const float* b1       = (const float*)d_in[18];
    const float* W2       = (const float*)d_in[19];
    const float* b2       = (const float*)d_in[20];

    char* ws = (char*)d_ws;
    float*          h      = (float*)ws;          ws += (size_t)NT * DIM * 4;
    unsigned short* hn     = (unsigned short*)ws; ws += (size_t)NT * DIM * 2;
    unsigned short* o      = (unsigned short*)ws; ws += (size_t)NT * DIM * 2;
    unsigned short* qkv    = (unsigned short*)ws; ws += (size_t)NT * FFD * 2;      // aliased qkv/ffn
    float*          Bg     = (float*)ws;          ws += (size_t)NG * 1024 * 4;
    unsigned short* Wqkv_t = (unsigned short*)ws; ws += (size_t)NLAY * 1536 * DIM * 2;
    unsigned short* Wo_t   = (unsigned short*)ws; ws += (size_t)NLAY * DIM * DIM * 2;
    unsigned short* W1_t   = (unsigned short*)ws; ws += (size_t)NLAY * FFD * DIM * 2;
    unsigned short* W2_t   = (unsigned short*)ws; ws += (size_t)NLAY * DIM * FFD * 2;
    float*          bqkv   = (float*)ws;          ws += (size_t)NLAY * 1536 * 4;
    unsigned short* ffnb   = qkv;

    // prep (1 launch)
    prep_all<<<14424, 256, 0, stream>>>(
        x, degrees, init_W, init_b, cent_emb, h, sp, db, vbias, Bg,
        Wq, Wk, Wv, bq, bk, bv, Wqkv_t, bqkv, Wo, W1, W2, Wo_t, W1_t, W2_t);

    for (int l = 0; l < NLAY - 1; ++l) {
        layernorm_bf16<<<NT, 256, 0, stream>>>(h, hn, 0, nullptr);
        gemm128<1><<<16 * 12, 256, 0, stream>>>(
            hn, Wqkv_t + (size_t)l * 1536 * DIM, bqkv + (size_t)l * 1536,
            qkv, 1536, DIM, /*bf16 out*/2, 16, 12);
        // fused attention + O-proj + residual
        attn_wo<<<NG * 4, 256, 0, stream>>>(
            qkv, Bg, Wo_t + (size_t)l * DIM * DIM, bo + (size_t)l * DIM, h);
        layernorm_bf16<<<NT, 256, 0, stream>>>(h, hn, 0, nullptr);
        gemm128<1><<<16 * 16, 256, 0, stream>>>(
            hn, W1_t + (size_t)l * FFD * DIM, b1 + (size_t)l * FFD,
            ffnb, FFD, DIM, /*relu+bf16*/3, 16, 16);
        gemm128<4><<<16 * 4 * 4, 256, 0, stream>>>(
            ffnb, W2_t + (size_t)l * DIM * FFD, b2 + (size_t)l * DIM,
            h, DIM, FFD, 0, 16, 4);
    }

    // ---- last layer: only virtual rows reach the output ----
    {
        int l = NLAY - 1;
        layernorm_bf16<<<NT, 256, 0, stream>>>(h, hn, 0, nullptr);
        // K,V for all rows; Q only for the panel containing virtual rows (flag 4)
        gemm128<1><<<16 * 12, 256, 0, stream>>>(
            hn, Wqkv_t + (size_t)l * 1536 * DIM, bqkv + (size_t)l * 1536,
            qkv, 1536, DIM, /*bf16 out + lastQKV*/6, 16, 12);
        attention_last<<<NG * NHD, 64, 0, stream>>>(qkv, Bg, o);
        gemm64<8><<<1 * 8 * 8, 256, 0, stream>>>(
            o, Wo_t + (size_t)l * DIM * DIM, bo + (size_t)l * DIM,
            h, DIM, DIM, NORI, 0, 1, 8, 0);
        // LN over virtual rows; seed d_out with the fp32 residual rows
        layernorm_bf16<<<NG, 256, 0, stream>>>(h, hn, NORI, (float*)d_out);
        gemm64<1><<<1 * 32, 256, 0, stream>>>(
            hn, W1_t + (size_t)l * FFD * DIM, b1 + (size_t)l * FFD,
            ffnb, FFD, DIM, NORI, 3, 1, 32, 0);
        // FFN2 accumulates directly into d_out (residual already there)
        gemm64<8><<<1 * 8 * 8, 256, 0, stream>>>(
            ffnb, W2_t + (size_t)l * DIM * FFD, b2 + (size_t)l * DIM,
            d_out, DIM, FFD, NORI, 0, 1, 8, NORI);
    }
}

// Round 12
// 409.716 us; speedup vs baseline: 1.3197x; 1.3197x over previous
//
#include <hip/hip_runtime.h>

// Graphormer encoder — bf16 MFMA GEMMs, fp32 residual path. Multi-dispatch.
// R20: R19's attn+Wo fusion reverted (84.6us/dispatch: serialized heads +
// 8-way o_lds bank conflict). Back to R16/R18 pipeline. GEMM occupancy fix:
// gemm128 tile 128x128 -> 128x64 (4 waves x 64x32, acc[4][2], 48KB LDS dbuf)
// doubling grids to 1.5-2 blocks/CU for cross-block latency hiding (m114) —
// previous grids were 1 block/CU = 1 wave/SIMD. Counted vmcnt(6) prefetch.

#define NG   64
#define NP   31
#define NORI 1984
#define NT   2048
#define DIM  512
#define NHD  8
#define DKH  64
#define FFD  2048
#define NLAY 4
#define NFEA 32

typedef __attribute__((ext_vector_type(8))) short short8;
typedef __attribute__((ext_vector_type(4))) float floatx4;

__device__ __forceinline__ unsigned short f2bf(float f) {
    union { float f; unsigned u; } v; v.f = f;
    unsigned r = v.u + 0x7fffu + ((v.u >> 16) & 1u);
    return (unsigned short)(r >> 16);
}
__device__ __forceinline__ float bf2f(unsigned short u) {
    union { unsigned u; float f; } v; v.u = ((unsigned)u) << 16;
    return v.f;
}

// ---------------------------------------------------------------- merged prep (1 dispatch)
__global__ __launch_bounds__(256) void prep_all(
    const float* __restrict__ x, const int* __restrict__ degrees,
    const float* __restrict__ init_W, const float* __restrict__ init_b,
    const float* __restrict__ cent_emb, float* __restrict__ h,
    const int* __restrict__ sp, const float* __restrict__ db,
    const float* __restrict__ virt_bias, float* __restrict__ Bg,
    const float* __restrict__ Wq, const float* __restrict__ Wk,
    const float* __restrict__ Wv, const float* __restrict__ bq,
    const float* __restrict__ bk, const float* __restrict__ bv,
    unsigned short* __restrict__ Wqkv_t, float* __restrict__ bqkv,
    const float* __restrict__ Wo, const float* __restrict__ W1,
    const float* __restrict__ W2, unsigned short* __restrict__ Wo_t,
    unsigned short* __restrict__ W1_t, unsigned short* __restrict__ W2_t)
{
    __shared__ float tl[32][33];
    int u = blockIdx.x;
    int tid = threadIdx.x;

    if (u < 2112) {                       // ---- init_h + build_B
        int n = u;
        if (n >= NT) {                    // B-build: one block per graph
            int g = n - NT;
            float vb = virt_bias[0];
            for (int e = tid; e < 1024; e += 256) {
                int i = e >> 5, j = e & 31;
                float v;
                if (i == j) v = db[0];
                else if (i < NP && j < NP) {
                    int s = sp[(size_t)(g * NP + i) * NORI + g * NP + j];
                    v = db[s < 100 ? s : 100];
                } else v = vb;
                Bg[(size_t)g * 1024 + e] = v;
            }
            return;
        }
        float* xs = &tl[0][0];
        if (n < NORI && tid < NFEA) xs[tid] = x[(size_t)n * NFEA + tid];
        __syncthreads();
        int deg = degrees[n]; if (deg > 100) deg = 100;
        for (int d = tid; d < DIM; d += 256) {
            float v = cent_emb[(size_t)deg * DIM + d];
            if (n < NORI) {
                float acc = init_b[d];
                #pragma unroll
                for (int k = 0; k < NFEA; ++k) acc += xs[k] * init_W[(size_t)k * DIM + d];
                v += acc;
            }
            h[(size_t)n * DIM + d] = v;
        }
        return;
    }
    if (u < 5208) {                       // ---- QKV weight transpose + bias
        int tile = u - 2112;
        if (tile >= 3072) {
            int idx = (tile - 3072) * 256 + tid;
            if (idx < NLAY * 1536) {
                int l = idx / 1536, c = idx % 1536;
                int which = c >> 9, cc = c & 511;
                const float* b = (which == 0) ? bq : (which == 1) ? bk : bv;
                bqkv[idx] = b[(size_t)l * 512 + cc];
            }
            return;
        }
        int slice = tile >> 5;
        int tloc = tile & 31;
        int dt = tloc >> 1, kt = tloc & 1;
        int l = slice / 24; int rem = slice % 24; int which = rem >> 3; int hh = rem & 7;
        const float* W = (which == 0) ? Wq : (which == 1) ? Wk : Wv;
        const float* in = W + (size_t)(l * 8 + hh) * DIM * DKH;
        int tr = tid >> 5, tc = tid & 31;
        #pragma unroll
        for (int pp = 0; pp < 4; ++pp)
            tl[tr + pp * 8][tc] = in[(size_t)(dt * 32 + tr + pp * 8) * DKH + kt * 32 + tc];
        __syncthreads();
        unsigned short* out = Wqkv_t +
            ((size_t)l * 1536 + which * 512 + hh * 64 + kt * 32) * DIM + dt * 32;
        #pragma unroll
        for (int pp = 0; pp < 4; ++pp)
            out[(size_t)(tr + pp * 8) * DIM + tc] = f2bf(tl[tc][tr + pp * 8]);
        return;
    }
    {                                     // ---- Wo/W1/W2 transpose
        int id = u - 5208;
        const float* in; unsigned short* outp; int R, C, l, rt, ct;
        if (id < 1024) {
            l = id >> 8; int t = id & 255; rt = t >> 4; ct = t & 15;
            in = Wo; outp = Wo_t; R = 512; C = 512;
        } else if (id < 5120) {
            int t2 = id - 1024; l = t2 >> 10; int t = t2 & 1023; rt = t >> 6; ct = t & 63;
            in = W1; outp = W1_t; R = 512; C = 2048;
        } else {
            int t2 = id - 5120; l = t2 >> 10; int t = t2 & 1023; rt = t >> 4; ct = t & 15;
            in = W2; outp = W2_t; R = 2048; C = 512;
        }
        const float* ip = in + (size_t)l * R * C;
        unsigned short* op = outp + (size_t)l * R * C;
        int r0 = rt * 32, c0 = ct * 32;
        int tr = tid >> 5, tc = tid & 31;
        #pragma unroll
        for (int pp = 0; pp < 4; ++pp)
            tl[tr + pp * 8][tc] = ip[(size_t)(r0 + tr + pp * 8) * C + c0 + tc];
        __syncthreads();
        #pragma unroll
        for (int pp = 0; pp < 4; ++pp)
            op[(size_t)(c0 + tr + pp * 8) * R + r0 + tc] = f2bf(tl[tc][tr + pp * 8]);
    }
}

// ---------------------------------------------------------------- layernorm: fp32 in -> bf16 out
__global__ __launch_bounds__(256) void layernorm_bf16(
    const float* __restrict__ in, unsigned short* __restrict__ out, int row0,
    float* __restrict__ fout)
{
    int n = row0 + blockIdx.x;
    int tid = threadIdx.x;
    const float* row = in + (size_t)n * DIM;
    float v0 = row[tid], v1 = row[tid + 256];
    float s = v0 + v1;
    float sq = v0 * v0 + v1 * v1;
    #pragma unroll
    for (int off = 32; off > 0; off >>= 1) {
        s  += __shfl_down(s, off);
        sq += __shfl_down(sq, off);
    }
    __shared__ float red[8];
    int wave = tid >> 6;
    if ((tid & 63) == 0) { red[wave] = s; red[4 + wave] = sq; }
    __syncthreads();
    float ts  = red[0] + red[1] + red[2] + red[3];
    float tsq = red[4] + red[5] + red[6] + red[7];
    float m   = ts * (1.0f / DIM);
    float var = tsq * (1.0f / DIM) - m * m;
    float inv = rsqrtf(var + 1e-5f);
    out[(size_t)n * DIM + tid]       = f2bf((v0 - m) * inv);
    out[(size_t)n * DIM + tid + 256] = f2bf((v1 - m) * inv);
    if (fout) {
        fout[(size_t)(n - row0) * DIM + tid]       = v0;
        fout[(size_t)(n - row0) * DIM + tid + 256] = v1;
    }
}

// ---------------------------------------------------------------- bf16 MFMA GEMM, 64-tile (small M)
template<int SPLITK>
__global__ __launch_bounds__(256) void gemm64(
    const unsigned short* __restrict__ A, const unsigned short* __restrict__ Bt,
    const float* __restrict__ bias, void* __restrict__ out,
    int Nfull, int K, int moff, int flags, int P, int C, int orow)
{
    __shared__ __align__(16) unsigned short Asl[64 * 72];
    __shared__ __align__(16) unsigned short Bsl[64 * 72];
    int id = blockIdx.x;
    int by, bx, bz;
    if (P >= 8) {
        int xcd = id & 7, t = id >> 3, G = P >> 3;
        by = xcd + 8 * (t % G);
        int r2 = t / G;
        bx = r2 % C;
        bz = r2 / C;
    } else {
        by = id % P; int r2 = id / P; bx = r2 % C; bz = r2 / C;
    }
    int tid = threadIdx.x;
    int row0 = moff + by * 64, col0 = bx * 64;
    if ((flags & 4) && col0 < 512 && row0 < NORI) return;
    int kslice = K / SPLITK;
    int kbeg = bz * kslice;
    int wave = tid >> 6, lane = tid & 63;
    int quad = lane >> 4, m16 = lane & 15;
    int mw = (wave >> 1) * 32, nw = (wave & 1) * 32;
    floatx4 acc[2][2] = {};
    for (int k0 = kbeg; k0 < kbeg + kslice; k0 += 64) {
        #pragma unroll
        for (int p = 0; p < 2; ++p) {
            int idx = (p * 256 + tid) * 8;
            int r = idx >> 6, kk = idx & 63;
            *(float4*)(Asl + r * 72 + kk) =
                *(const float4*)(A + (size_t)(row0 + r) * K + k0 + kk);
            *(float4*)(Bsl + r * 72 + kk) =
                *(const float4*)(Bt + (size_t)(col0 + r) * K + k0 + kk);
        }
        __syncthreads();
        #pragma unroll
        for (int ks = 0; ks < 64; ks += 32) {
            short8 a[2], b[2];
            #pragma unroll
            for (int mi = 0; mi < 2; ++mi)
                a[mi] = *(const short8*)(Asl + (mw + mi * 16 + m16) * 72 + ks + quad * 8);
            #pragma unroll
            for (int ni = 0; ni < 2; ++ni)
                b[ni] = *(const short8*)(Bsl + (nw + ni * 16 + m16) * 72 + ks + quad * 8);
            #pragma unroll
            for (int mi = 0; mi < 2; ++mi)
                #pragma unroll
                for (int ni = 0; ni < 2; ++ni)
                    acc[mi][ni] = __builtin_amdgcn_mfma_f32_16x16x32_bf16(
                        a[mi], b[ni], acc[mi][ni], 0, 0, 0);
        }
        __syncthreads();
    }
    if (SPLITK == 1) {
        int do_relu = flags & 1, out_bf = flags & 2;
        #pragma unroll
        for (int mi = 0; mi < 2; ++mi) {
            #pragma unroll
            for (int ni = 0; ni < 2; ++ni) {
                int col = col0 + nw + ni * 16 + m16;
                float bval = bias[col];
                #pragma unroll
                for (int rr = 0; rr < 4; ++rr) {
                    int row = row0 + mw + mi * 16 + quad * 4 + rr;
                    float v = acc[mi][ni][rr] + bval;
                    if (do_relu) v = fmaxf(v, 0.0f);
                    if (out_bf) ((unsigned short*)out)[(size_t)(row - orow) * Nfull + col] = f2bf(v);
                    else        ((float*)out)[(size_t)(row - orow) * Nfull + col] = v;
                }
            }
        }
    } else {
        float* o = (float*)out;
        float bscale = (bz == 0) ? 1.0f : 0.0f;
        #pragma unroll
        for (int mi = 0; mi < 2; ++mi) {
            #pragma unroll
            for (int ni = 0; ni < 2; ++ni) {
                int col = col0 + nw + ni * 16 + m16;
                float bval = bias[col] * bscale;
                #pragma unroll
                for (int rr = 0; rr < 4; ++rr) {
                    int row = row0 + mw + mi * 16 + quad * 4 + rr;
                    atomicAdd(&o[(size_t)(row - orow) * Nfull + col],
                              acc[mi][ni][rr] + bval);
                }
            }
        }
    }
}

// ---------------------------------------------------------------- bf16 MFMA GEMM, 128x64-tile
// 4 waves, each 64x32 (4x2 frags). 2-phase dbuf, counted vmcnt(6).
// A: 16 chunks of 1024B (rows 0..127); B: 8 chunks (rows 0..63).
__device__ __forceinline__ void stage12864(
    const unsigned short* __restrict__ Abase, const unsigned short* __restrict__ Bbase,
    int K, int k0, unsigned short* Asl, unsigned short* Bsl,
    int wave, int lane, int lr, int scol)
{
    #pragma unroll
    for (int p = 0; p < 4; ++p) {
        int chunk = wave * 4 + p;
        int r = chunk * 8 + lr;
        __builtin_amdgcn_global_load_lds(
            (const __attribute__((address_space(1))) unsigned int*)
                (Abase + (size_t)r * K + k0 + scol),
            (__attribute__((address_space(3))) unsigned int*)
                (Asl + chunk * 512 + lane * 8), 16, 0, 0);
    }
    #pragma unroll
    for (int p = 0; p < 2; ++p) {
        int chunk = wave * 2 + p;
        int r = chunk * 8 + lr;
        __builtin_amdgcn_global_load_lds(
            (const __attribute__((address_space(1))) unsigned int*)
                (Bbase + (size_t)r * K + k0 + scol),
            (__attribute__((address_space(3))) unsigned int*)
                (Bsl + chunk * 512 + lane * 8), 16, 0, 0);
    }
}

template<int SPLITK>
__global__ __launch_bounds__(256) void gemm128(
    const unsigned short* __restrict__ A, const unsigned short* __restrict__ Bt,
    const float* __restrict__ bias, void* __restrict__ out,
    int Nfull, int K, int flags, int P, int C)
{
    __shared__ __align__(16) unsigned short Asl[2][128 * 64];
    __shared__ __align__(16) unsigned short Bsl[2][64 * 64];
    int id = blockIdx.x;
    int xcd = id & 7, t = id >> 3, Gp = P >> 3;
    int by = xcd + 8 * (t % Gp);
    int r2 = t / Gp;
    int bx = r2 % C;
    int bz = r2 / C;
    int tid = threadIdx.x;
    int row0 = by * 128, col0 = bx * 64;
    if ((flags & 4) && col0 < 512 && row0 + 128 <= NORI) return;   // Q only for virt panel
    int kslice = K / SPLITK;
    int kbeg = bz * kslice;
    int nk = kslice >> 6;
    int wave = tid >> 6, lane = tid & 63;
    int quad = lane >> 4, m16 = lane & 15;
    int mw = (wave >> 1) * 64, nw = (wave & 1) * 32;
    int lr = lane >> 3;
    int scol = ((lane & 7) ^ lr) << 3;
    int rdswz = (m16 & 7) << 4;
    const unsigned short* Abase = A + (size_t)row0 * K;
    const unsigned short* Bbase = Bt + (size_t)col0 * K;
    floatx4 acc[4][2] = {};

    stage12864(Abase, Bbase, K, kbeg, Asl[0], Bsl[0], wave, lane, lr, scol);
    int cur = 0;
    for (int i = 0; i < nk; ++i) {
        if (i + 1 < nk) {
            stage12864(Abase, Bbase, K, kbeg + (i + 1) * 64,
                       Asl[cur ^ 1], Bsl[cur ^ 1], wave, lane, lr, scol);
            asm volatile("s_waitcnt vmcnt(6)" ::: "memory");   // current tile landed
        } else {
            asm volatile("s_waitcnt vmcnt(0)" ::: "memory");
        }
        __builtin_amdgcn_s_barrier();
        const char* Ac = (const char*)Asl[cur];
        const char* Bc = (const char*)Bsl[cur];
        #pragma unroll
        for (int ks = 0; ks < 64; ks += 32) {
            short8 a[4], b[2];
            int cb = (ks + quad * 8) * 2;
            #pragma unroll
            for (int mi = 0; mi < 4; ++mi)
                a[mi] = *(const short8*)(Ac + (mw + mi * 16 + m16) * 128 + (cb ^ rdswz));
            #pragma unroll
            for (int ni = 0; ni < 2; ++ni)
                b[ni] = *(const short8*)(Bc + (nw + ni * 16 + m16) * 128 + (cb ^ rdswz));
            #pragma unroll
            for (int mi = 0; mi < 4; ++mi)
                #pragma unroll
                for (int ni = 0; ni < 2; ++ni)
                    acc[mi][ni] = __builtin_amdgcn_mfma_f32_16x16x32_bf16(
                        a[mi], b[ni], acc[mi][ni], 0, 0, 0);
        }
        __builtin_amdgcn_s_barrier();
        asm volatile("" ::: "memory");
        cur ^= 1;
    }
    if (SPLITK == 1) {
        int do_relu = flags & 1, out_bf = flags & 2;
        #pragma unroll
        for (int mi = 0; mi < 4; ++mi) {
            #pragma unroll
            for (int ni = 0; ni < 2; ++ni) {
                int col = col0 + nw + ni * 16 + m16;
                float bval = bias[col];
                #pragma unroll
                for (int rr = 0; rr < 4; ++rr) {
                    int row = row0 + mw + mi * 16 + quad * 4 + rr;
                    float v = acc[mi][ni][rr] + bval;
                    if (do_relu) v = fmaxf(v, 0.0f);
                    if (out_bf) ((unsigned short*)out)[(size_t)row * Nfull + col] = f2bf(v);
                    else        ((float*)out)[(size_t)row * Nfull + col] = v;
                }
            }
        }
    } else {
        float* o = (float*)out;
        float bscale = (bz == 0) ? 1.0f : 0.0f;
        #pragma unroll
        for (int mi = 0; mi < 4; ++mi) {
            #pragma unroll
            for (int ni = 0; ni < 2; ++ni) {
                int col = col0 + nw + ni * 16 + m16;
                float bval = bias[col] * bscale;
                #pragma unroll
                for (int rr = 0; rr < 4; ++rr) {
                    int row = row0 + mw + mi * 16 + quad * 4 + rr;
                    atomicAdd(&o[(size_t)row * Nfull + col], acc[mi][ni][rr] + bval);
                }
            }
        }
    }
}

// ---------------------------------------------------------------- block attention (layers 0..2)
__global__ __launch_bounds__(256) void attention(
    const unsigned short* __restrict__ qkv,  // [NT][1536] bf16, Q|K|V head-major
    const float* __restrict__ Bg,            // [NG][32][32]
    unsigned short* __restrict__ O)          // [NT][512] bf16 head-major
{
    int g = blockIdx.x >> 3;
    int hh = blockIdx.x & 7;
    __shared__ float Qs[32][65], Ks[32][65], Vs[32][65];
    __shared__ float S[32][33];
    int tid = threadIdx.x;
    int i = tid >> 3;
    int c0 = (tid & 7) * 8;
    int gn = (i < NP) ? g * NP + i : NORI + g;
    const unsigned short* base = qkv + (size_t)gn * 1536 + hh * DKH;
    short8 qv = *(const short8*)(base + c0);
    short8 kv = *(const short8*)(base + 512 + c0);
    short8 vv = *(const short8*)(base + 1024 + c0);
    #pragma unroll
    for (int j = 0; j < 8; ++j) {
        Qs[i][c0 + j] = bf2f((unsigned short)qv[j]);
        Ks[i][c0 + j] = bf2f((unsigned short)kv[j]);
        Vs[i][c0 + j] = bf2f((unsigned short)vv[j]);
    }
    __syncthreads();
    const float scale = 0.125f;
    #pragma unroll
    for (int e = 0; e < 4; ++e) {
        int idx = tid + e * 256;
        int si = idx >> 5, sj = idx & 31;
        float dot = 0.0f;
        #pragma unroll
        for (int k = 0; k < DKH; ++k) dot += Qs[si][k] * Ks[sj][k];
        S[si][sj] = dot * scale + Bg[(size_t)g * 1024 + si * 32 + sj];
    }
    __syncthreads();
    if (tid < 32) {
        float mx = -1e30f;
        #pragma unroll
        for (int j = 0; j < 32; ++j) mx = fmaxf(mx, S[tid][j]);
        float sum = 0.0f;
        #pragma unroll
        for (int j = 0; j < 32; ++j) { float e = __expf(S[tid][j] - mx); S[tid][j] = e; sum += e; }
        float inv = 1.0f / sum;
        #pragma unroll
        for (int j = 0; j < 32; ++j) S[tid][j] *= inv;
    }
    __syncthreads();
    short8 ov;
    #pragma unroll
    for (int cc = 0; cc < 8; ++cc) {
        float acc = 0.0f;
        #pragma unroll
        for (int j = 0; j < 32; ++j) acc += S[i][j] * Vs[j][c0 + cc];
        ov[cc] = (short)f2bf(acc);
    }
    *(short8*)(O + (size_t)gn * DIM + hh * DKH + c0) = ov;
}

// ---------------------------------------------------------------- last-layer attention
__global__ __launch_bounds__(64) void attention_last(
    const unsigned short* __restrict__ qkv, const float* __restrict__ Bg,
    unsigned short* __restrict__ O)
{
    int g = blockIdx.x >> 3, hh = blockIdx.x & 7;
    __shared__ float Ks[32][65], Vs[32][65];
    __shared__ float Qs[64], P[32];
    int tid = threadIdx.x;
    int j = tid & 31, hf = tid >> 5;
    int gn = (j < NP) ? g * NP + j : NORI + g;
    const unsigned short* kb = qkv + (size_t)gn * 1536 + hh * DKH + 512 + hf * 32;
    #pragma unroll
    for (int c = 0; c < 32; c += 8) {
        short8 k8 = *(const short8*)(kb + c);
        short8 v8 = *(const short8*)(kb + 512 + c);
        #pragma unroll
        for (int t = 0; t < 8; ++t) {
            Ks[j][hf * 32 + c + t] = bf2f((unsigned short)k8[t]);
            Vs[j][hf * 32 + c + t] = bf2f((unsigned short)v8[t]);
        }
    }
    Qs[tid] = bf2f(qkv[(size_t)(NORI + g) * 1536 + hh * DKH + tid]);
    __syncthreads();
    float s;
    if (tid < 32) {
        float dot = 0.0f;
        #pragma unroll
        for (int k = 0; k < 64; ++k) dot += Qs[k] * Ks[tid][k];
        s = dot * 0.125f + Bg[(size_t)g * 1024 + 31 * 32 + tid];
    } else s = -1e30f;
    float mx = s;
    #pragma unroll
    for (int off = 32; off > 0; off >>= 1) mx = fmaxf(mx, __shfl_xor(mx, off));
    float e = (tid < 32) ? __expf(s - mx) : 0.0f;
    float sum = e;
    #pragma unroll
    for (int off = 32; off > 0; off >>= 1) sum += __shfl_xor(sum, off);
    if (tid < 32) P[tid] = e / sum;
    __syncthreads();
    float acc = 0.0f;
    #pragma unroll
    for (int jj = 0; jj < 32; ++jj) acc += P[jj] * Vs[jj][tid];
    O[(size_t)(NORI + g) * DIM + hh * DKH + tid] = f2bf(acc);
}

// ---------------------------------------------------------------- launch
extern "C" void kernel_launch(void* const* d_in, const int* in_sizes, int n_in,
                              void* d_out, int out_size, void* d_ws, size_t ws_size,
                              hipStream_t stream)
{
    const float* x        = (const float*)d_in[0];
    const int*   sp       = (const int*)d_in[1];
    const int*   degrees  = (const int*)d_in[3];
    const float* init_W   = (const float*)d_in[4];
    const float* init_b   = (const float*)d_in[5];
    const float* cent_emb = (const float*)d_in[6];
    const float* db       = (const float*)d_in[7];
    const float* vbias    = (const float*)d_in[8];
    const float* Wq       = (const float*)d_in[9];
    const float* bq       = (const float*)d_in[10];
    const float* Wk       = (const float*)d_in[11];
    const float* bk       = (const float*)d_in[12];
    const float* Wv       = (const float*)d_in[13];
    const float* bv       = (const float*)d_in[14];
    const float* Wo       = (const float*)d_in[15];
    const float* bo       = (const float*)d_in[16];
    const float* W1       = (const float*)d_in[17];
    const float* b1       = (const float*)d_in[18];
    const float* W2       = (const float*)d_in[19];
    const float* b2       = (const float*)d_in[20];

    char* ws = (char*)d_ws;
    float*          h      = (float*)ws;          ws += (size_t)NT * DIM * 4;
    unsigned short* hn     = (unsigned short*)ws; ws += (size_t)NT * DIM * 2;
    unsigned short* o      = (unsigned short*)ws; ws += (size_t)NT * DIM * 2;
    unsigned short* qkv    = (unsigned short*)ws; ws += (size_t)NT * FFD * 2;      // aliased qkv/ffn
    float*          Bg     = (float*)ws;          ws += (size_t)NG * 1024 * 4;
    unsigned short* Wqkv_t = (unsigned short*)ws; ws += (size_t)NLAY * 1536 * DIM * 2;
    unsigned short* Wo_t   = (unsigned short*)ws; ws += (size_t)NLAY * DIM * DIM * 2;
    unsigned short* W1_t   = (unsigned short*)ws; ws += (size_t)NLAY * FFD * DIM * 2;
    unsigned short* W2_t   = (unsigned short*)ws; ws += (size_t)NLAY * DIM * FFD * 2;
    float*          bqkv   = (float*)ws;          ws += (size_t)NLAY * 1536 * 4;
    unsigned short* ffnb   = qkv;

    // prep (1 launch)
    prep_all<<<14424, 256, 0, stream>>>(
        x, degrees, init_W, init_b, cent_emb, h, sp, db, vbias, Bg,
        Wq, Wk, Wv, bq, bk, bv, Wqkv_t, bqkv, Wo, W1, W2, Wo_t, W1_t, W2_t);

    for (int l = 0; l < NLAY - 1; ++l) {
        layernorm_bf16<<<NT, 256, 0, stream>>>(h, hn, 0, nullptr);
        gemm128<1><<<16 * 24, 256, 0, stream>>>(
            hn, Wqkv_t + (size_t)l * 1536 * DIM, bqkv + (size_t)l * 1536,
            qkv, 1536, DIM, /*bf16 out*/2, 16, 24);
        attention<<<NG * NHD, 256, 0, stream>>>(qkv, Bg, o);
        gemm128<2><<<16 * 8 * 2, 256, 0, stream>>>(
            o, Wo_t + (size_t)l * DIM * DIM, bo + (size_t)l * DIM,
            h, DIM, DIM, 0, 16, 8);
        layernorm_bf16<<<NT, 256, 0, stream>>>(h, hn, 0, nullptr);
        gemm128<1><<<16 * 32, 256, 0, stream>>>(
            hn, W1_t + (size_t)l * FFD * DIM, b1 + (size_t)l * FFD,
            ffnb, FFD, DIM, /*relu+bf16*/3, 16, 32);
        gemm128<4><<<16 * 8 * 4, 256, 0, stream>>>(
            ffnb, W2_t + (size_t)l * DIM * FFD, b2 + (size_t)l * DIM,
            h, DIM, FFD, 0, 16, 8);
    }

    // ---- last layer: only virtual rows reach the output ----
    {
        int l = NLAY - 1;
        layernorm_bf16<<<NT, 256, 0, stream>>>(h, hn, 0, nullptr);
        // K,V for all rows; Q only for the panel containing virtual rows (flag 4)
        gemm128<1><<<16 * 24, 256, 0, stream>>>(
            hn, Wqkv_t + (size_t)l * 1536 * DIM, bqkv + (size_t)l * 1536,
            qkv, 1536, DIM, /*bf16 out + lastQKV*/6, 16, 24);
        attention_last<<<NG * NHD, 64, 0, stream>>>(qkv, Bg, o);
        gemm64<8><<<1 * 8 * 8, 256, 0, stream>>>(
            o, Wo_t + (size_t)l * DIM * DIM, bo + (size_t)l * DIM,
            h, DIM, DIM, NORI, 0, 1, 8, 0);
        // LN over virtual rows; seed d_out with the fp32 residual rows
        layernorm_bf16<<<NG, 256, 0, stream>>>(h, hn, NORI, (float*)d_out);
        gemm64<1><<<1 * 32, 256, 0, stream>>>(
            hn, W1_t + (size_t)l * FFD * DIM, b1 + (size_t)l * FFD,
            ffnb, FFD, DIM, NORI, 3, 1, 32, 0);
        // FFN2 accumulates directly into d_out (residual already there)
        gemm64<8><<<1 * 8 * 8, 256, 0, stream>>>(
            ffnb, W2_t + (size_t)l * DIM * FFD, b2 + (size_t)l * DIM,
            d_out, DIM, FFD, NORI, 0, 1, 8, NORI);
    }
}

// Round 13
// 409.633 us; speedup vs baseline: 1.3199x; 1.0002x over previous
//
#include <hip/hip_runtime.h>

// Graphormer encoder — bf16 MFMA GEMMs, fp32 residual path. Multi-dispatch.
// R21: occupancy lever iterated (R20 win: 452->409.7 with 128x64 tiles).
//  - QKV & FFN1 -> gemm64g 64x64 tiles (global_load_lds+swizzle+dbuf,
//    vmcnt(4), 32KB LDS): grids 768 / 1024 blocks = 3-4 blocks/CU.
//  - Wo-proj split-K 2 -> 4 on the 128x64 kernel: 512 blocks = 2/CU.
// All staging/swizzle/epilogue patterns carried from verified kernels.

#define NG   64
#define NP   31
#define NORI 1984
#define NT   2048
#define DIM  512
#define NHD  8
#define DKH  64
#define FFD  2048
#define NLAY 4
#define NFEA 32

typedef __attribute__((ext_vector_type(8))) short short8;
typedef __attribute__((ext_vector_type(4))) float floatx4;

__device__ __forceinline__ unsigned short f2bf(float f) {
    union { float f; unsigned u; } v; v.f = f;
    unsigned r = v.u + 0x7fffu + ((v.u >> 16) & 1u);
    return (unsigned short)(r >> 16);
}
__device__ __forceinline__ float bf2f(unsigned short u) {
    union { unsigned u; float f; } v; v.u = ((unsigned)u) << 16;
    return v.f;
}

// ---------------------------------------------------------------- merged prep (1 dispatch)
__global__ __launch_bounds__(256) void prep_all(
    const float* __restrict__ x, const int* __restrict__ degrees,
    const float* __restrict__ init_W, const float* __restrict__ init_b,
    const float* __restrict__ cent_emb, float* __restrict__ h,
    const int* __restrict__ sp, const float* __restrict__ db,
    const float* __restrict__ virt_bias, float* __restrict__ Bg,
    const float* __restrict__ Wq, const float* __restrict__ Wk,
    const float* __restrict__ Wv, const float* __restrict__ bq,
    const float* __restrict__ bk, const float* __restrict__ bv,
    unsigned short* __restrict__ Wqkv_t, float* __restrict__ bqkv,
    const float* __restrict__ Wo, const float* __restrict__ W1,
    const float* __restrict__ W2, unsigned short* __restrict__ Wo_t,
    unsigned short* __restrict__ W1_t, unsigned short* __restrict__ W2_t)
{
    __shared__ float tl[32][33];
    int u = blockIdx.x;
    int tid = threadIdx.x;

    if (u < 2112) {                       // ---- init_h + build_B
        int n = u;
        if (n >= NT) {                    // B-build: one block per graph
            int g = n - NT;
            float vb = virt_bias[0];
            for (int e = tid; e < 1024; e += 256) {
                int i = e >> 5, j = e & 31;
                float v;
                if (i == j) v = db[0];
                else if (i < NP && j < NP) {
                    int s = sp[(size_t)(g * NP + i) * NORI + g * NP + j];
                    v = db[s < 100 ? s : 100];
                } else v = vb;
                Bg[(size_t)g * 1024 + e] = v;
            }
            return;
        }
        float* xs = &tl[0][0];
        if (n < NORI && tid < NFEA) xs[tid] = x[(size_t)n * NFEA + tid];
        __syncthreads();
        int deg = degrees[n]; if (deg > 100) deg = 100;
        for (int d = tid; d < DIM; d += 256) {
            float v = cent_emb[(size_t)deg * DIM + d];
            if (n < NORI) {
                float acc = init_b[d];
                #pragma unroll
                for (int k = 0; k < NFEA; ++k) acc += xs[k] * init_W[(size_t)k * DIM + d];
                v += acc;
            }
            h[(size_t)n * DIM + d] = v;
        }
        return;
    }
    if (u < 5208) {                       // ---- QKV weight transpose + bias
        int tile = u - 2112;
        if (tile >= 3072) {
            int idx = (tile - 3072) * 256 + tid;
            if (idx < NLAY * 1536) {
                int l = idx / 1536, c = idx % 1536;
                int which = c >> 9, cc = c & 511;
                const float* b = (which == 0) ? bq : (which == 1) ? bk : bv;
                bqkv[idx] = b[(size_t)l * 512 + cc];
            }
            return;
        }
        int slice = tile >> 5;
        int tloc = tile & 31;
        int dt = tloc >> 1, kt = tloc & 1;
        int l = slice / 24; int rem = slice % 24; int which = rem >> 3; int hh = rem & 7;
        const float* W = (which == 0) ? Wq : (which == 1) ? Wk : Wv;
        const float* in = W + (size_t)(l * 8 + hh) * DIM * DKH;
        int tr = tid >> 5, tc = tid & 31;
        #pragma unroll
        for (int pp = 0; pp < 4; ++pp)
            tl[tr + pp * 8][tc] = in[(size_t)(dt * 32 + tr + pp * 8) * DKH + kt * 32 + tc];
        __syncthreads();
        unsigned short* out = Wqkv_t +
            ((size_t)l * 1536 + which * 512 + hh * 64 + kt * 32) * DIM + dt * 32;
        #pragma unroll
        for (int pp = 0; pp < 4; ++pp)
            out[(size_t)(tr + pp * 8) * DIM + tc] = f2bf(tl[tc][tr + pp * 8]);
        return;
    }
    {                                     // ---- Wo/W1/W2 transpose
        int id = u - 5208;
        const float* in; unsigned short* outp; int R, C, l, rt, ct;
        if (id < 1024) {
            l = id >> 8; int t = id & 255; rt = t >> 4; ct = t & 15;
            in = Wo; outp = Wo_t; R = 512; C = 512;
        } else if (id < 5120) {
            int t2 = id - 1024; l = t2 >> 10; int t = t2 & 1023; rt = t >> 6; ct = t & 63;
            in = W1; outp = W1_t; R = 512; C = 2048;
        } else {
            int t2 = id - 5120; l = t2 >> 10; int t = t2 & 1023; rt = t >> 4; ct = t & 15;
            in = W2; outp = W2_t; R = 2048; C = 512;
        }
        const float* ip = in + (size_t)l * R * C;
        unsigned short* op = outp + (size_t)l * R * C;
        int r0 = rt * 32, c0 = ct * 32;
        int tr = tid >> 5, tc = tid & 31;
        #pragma unroll
        for (int pp = 0; pp < 4; ++pp)
            tl[tr + pp * 8][tc] = ip[(size_t)(r0 + tr + pp * 8) * C + c0 + tc];
        __syncthreads();
        #pragma unroll
        for (int pp = 0; pp < 4; ++pp)
            op[(size_t)(c0 + tr + pp * 8) * R + r0 + tc] = f2bf(tl[tc][tr + pp * 8]);
    }
}

// ---------------------------------------------------------------- layernorm: fp32 in -> bf16 out
__global__ __launch_bounds__(256) void layernorm_bf16(
    const float* __restrict__ in, unsigned short* __restrict__ out, int row0,
    float* __restrict__ fout)
{
    int n = row0 + blockIdx.x;
    int tid = threadIdx.x;
    const float* row = in + (size_t)n * DIM;
    float v0 = row[tid], v1 = row[tid + 256];
    float s = v0 + v1;
    float sq = v0 * v0 + v1 * v1;
    #pragma unroll
    for (int off = 32; off > 0; off >>= 1) {
        s  += __shfl_down(s, off);
        sq += __shfl_down(sq, off);
    }
    __shared__ float red[8];
    int wave = tid >> 6;
    if ((tid & 63) == 0) { red[wave] = s; red[4 + wave] = sq; }
    __syncthreads();
    float ts  = red[0] + red[1] + red[2] + red[3];
    float tsq = red[4] + red[5] + red[6] + red[7];
    float m   = ts * (1.0f / DIM);
    float var = tsq * (1.0f / DIM) - m * m;
    float inv = rsqrtf(var + 1e-5f);
    out[(size_t)n * DIM + tid]       = f2bf((v0 - m) * inv);
    out[(size_t)n * DIM + tid + 256] = f2bf((v1 - m) * inv);
    if (fout) {
        fout[(size_t)(n - row0) * DIM + tid]       = v0;
        fout[(size_t)(n - row0) * DIM + tid + 256] = v1;
    }
}

// ---------------------------------------------------------------- bf16 MFMA GEMM, 64-tile (small M)
template<int SPLITK>
__global__ __launch_bounds__(256) void gemm64(
    const unsigned short* __restrict__ A, const unsigned short* __restrict__ Bt,
    const float* __restrict__ bias, void* __restrict__ out,
    int Nfull, int K, int moff, int flags, int P, int C, int orow)
{
    __shared__ __align__(16) unsigned short Asl[64 * 72];
    __shared__ __align__(16) unsigned short Bsl[64 * 72];
    int id = blockIdx.x;
    int by, bx, bz;
    if (P >= 8) {
        int xcd = id & 7, t = id >> 3, G = P >> 3;
        by = xcd + 8 * (t % G);
        int r2 = t / G;
        bx = r2 % C;
        bz = r2 / C;
    } else {
        by = id % P; int r2 = id / P; bx = r2 % C; bz = r2 / C;
    }
    int tid = threadIdx.x;
    int row0 = moff + by * 64, col0 = bx * 64;
    if ((flags & 4) && col0 < 512 && row0 < NORI) return;
    int kslice = K / SPLITK;
    int kbeg = bz * kslice;
    int wave = tid >> 6, lane = tid & 63;
    int quad = lane >> 4, m16 = lane & 15;
    int mw = (wave >> 1) * 32, nw = (wave & 1) * 32;
    floatx4 acc[2][2] = {};
    for (int k0 = kbeg; k0 < kbeg + kslice; k0 += 64) {
        #pragma unroll
        for (int p = 0; p < 2; ++p) {
            int idx = (p * 256 + tid) * 8;
            int r = idx >> 6, kk = idx & 63;
            *(float4*)(Asl + r * 72 + kk) =
                *(const float4*)(A + (size_t)(row0 + r) * K + k0 + kk);
            *(float4*)(Bsl + r * 72 + kk) =
                *(const float4*)(Bt + (size_t)(col0 + r) * K + k0 + kk);
        }
        __syncthreads();
        #pragma unroll
        for (int ks = 0; ks < 64; ks += 32) {
            short8 a[2], b[2];
            #pragma unroll
            for (int mi = 0; mi < 2; ++mi)
                a[mi] = *(const short8*)(Asl + (mw + mi * 16 + m16) * 72 + ks + quad * 8);
            #pragma unroll
            for (int ni = 0; ni < 2; ++ni)
                b[ni] = *(const short8*)(Bsl + (nw + ni * 16 + m16) * 72 + ks + quad * 8);
            #pragma unroll
            for (int mi = 0; mi < 2; ++mi)
                #pragma unroll
                for (int ni = 0; ni < 2; ++ni)
                    acc[mi][ni] = __builtin_amdgcn_mfma_f32_16x16x32_bf16(
                        a[mi], b[ni], acc[mi][ni], 0, 0, 0);
        }
        __syncthreads();
    }
    if (SPLITK == 1) {
        int do_relu = flags & 1, out_bf = flags & 2;
        #pragma unroll
        for (int mi = 0; mi < 2; ++mi) {
            #pragma unroll
            for (int ni = 0; ni < 2; ++ni) {
                int col = col0 + nw + ni * 16 + m16;
                float bval = bias[col];
                #pragma unroll
                for (int rr = 0; rr < 4; ++rr) {
                    int row = row0 + mw + mi * 16 + quad * 4 + rr;
                    float v = acc[mi][ni][rr] + bval;
                    if (do_relu) v = fmaxf(v, 0.0f);
                    if (out_bf) ((unsigned short*)out)[(size_t)(row - orow) * Nfull + col] = f2bf(v);
                    else        ((float*)out)[(size_t)(row - orow) * Nfull + col] = v;
                }
            }
        }
    } else {
        float* o = (float*)out;
        float bscale = (bz == 0) ? 1.0f : 0.0f;
        #pragma unroll
        for (int mi = 0; mi < 2; ++mi) {
            #pragma unroll
            for (int ni = 0; ni < 2; ++ni) {
                int col = col0 + nw + ni * 16 + m16;
                float bval = bias[col] * bscale;
                #pragma unroll
                for (int rr = 0; rr < 4; ++rr) {
                    int row = row0 + mw + mi * 16 + quad * 4 + rr;
                    atomicAdd(&o[(size_t)(row - orow) * Nfull + col],
                              acc[mi][ni][rr] + bval);
                }
            }
        }
    }
}

// ---------------------------------------------------------------- bf16 MFMA GEMM, 64x64-tile DMA
// 4 waves, each 32x32 (2x2 frags). global_load_lds dbuf, counted vmcnt(4).
__device__ __forceinline__ void stage64g(
    const unsigned short* __restrict__ Abase, const unsigned short* __restrict__ Bbase,
    int K, int k0, unsigned short* Asl, unsigned short* Bsl,
    int wave, int lane, int lr, int scol)
{
    #pragma unroll
    for (int p = 0; p < 2; ++p) {
        int chunk = wave * 2 + p;
        int r = chunk * 8 + lr;
        __builtin_amdgcn_global_load_lds(
            (const __attribute__((address_space(1))) unsigned int*)
                (Abase + (size_t)r * K + k0 + scol),
            (__attribute__((address_space(3))) unsigned int*)
                (Asl + chunk * 512 + lane * 8), 16, 0, 0);
        __builtin_amdgcn_global_load_lds(
            (const __attribute__((address_space(1))) unsigned int*)
                (Bbase + (size_t)r * K + k0 + scol),
            (__attribute__((address_space(3))) unsigned int*)
                (Bsl + chunk * 512 + lane * 8), 16, 0, 0);
    }
}

template<int SPLITK>
__global__ __launch_bounds__(256) void gemm64g(
    const unsigned short* __restrict__ A, const unsigned short* __restrict__ Bt,
    const float* __restrict__ bias, void* __restrict__ out,
    int Nfull, int K, int flags, int P, int C)
{
    __shared__ __align__(16) unsigned short Asl[2][64 * 64];
    __shared__ __align__(16) unsigned short Bsl[2][64 * 64];
    int id = blockIdx.x;
    int xcd = id & 7, t = id >> 3, Gp = P >> 3;
    int by = xcd + 8 * (t % Gp);
    int r2 = t / Gp;
    int bx = r2 % C;
    int bz = r2 / C;
    int tid = threadIdx.x;
    int row0 = by * 64, col0 = bx * 64;
    if ((flags & 4) && col0 < 512 && row0 + 64 <= NORI) return;   // Q only for virt panel
    int kslice = K / SPLITK;
    int kbeg = bz * kslice;
    int nk = kslice >> 6;
    int wave = tid >> 6, lane = tid & 63;
    int quad = lane >> 4, m16 = lane & 15;
    int mw = (wave >> 1) * 32, nw = (wave & 1) * 32;
    int lr = lane >> 3;
    int scol = ((lane & 7) ^ lr) << 3;
    int rdswz = (m16 & 7) << 4;
    const unsigned short* Abase = A + (size_t)row0 * K;
    const unsigned short* Bbase = Bt + (size_t)col0 * K;
    floatx4 acc[2][2] = {};

    stage64g(Abase, Bbase, K, kbeg, Asl[0], Bsl[0], wave, lane, lr, scol);
    int cur = 0;
    for (int i = 0; i < nk; ++i) {
        if (i + 1 < nk) {
            stage64g(Abase, Bbase, K, kbeg + (i + 1) * 64,
                     Asl[cur ^ 1], Bsl[cur ^ 1], wave, lane, lr, scol);
            asm volatile("s_waitcnt vmcnt(4)" ::: "memory");   // current tile landed
        } else {
            asm volatile("s_waitcnt vmcnt(0)" ::: "memory");
        }
        __builtin_amdgcn_s_barrier();
        const char* Ac = (const char*)Asl[cur];
        const char* Bc = (const char*)Bsl[cur];
        #pragma unroll
        for (int ks = 0; ks < 64; ks += 32) {
            short8 a[2], b[2];
            int cb = (ks + quad * 8) * 2;
            #pragma unroll
            for (int mi = 0; mi < 2; ++mi)
                a[mi] = *(const short8*)(Ac + (mw + mi * 16 + m16) * 128 + (cb ^ rdswz));
            #pragma unroll
            for (int ni = 0; ni < 2; ++ni)
                b[ni] = *(const short8*)(Bc + (nw + ni * 16 + m16) * 128 + (cb ^ rdswz));
            #pragma unroll
            for (int mi = 0; mi < 2; ++mi)
                #pragma unroll
                for (int ni = 0; ni < 2; ++ni)
                    acc[mi][ni] = __builtin_amdgcn_mfma_f32_16x16x32_bf16(
                        a[mi], b[ni], acc[mi][ni], 0, 0, 0);
        }
        __builtin_amdgcn_s_barrier();
        asm volatile("" ::: "memory");
        cur ^= 1;
    }
    if (SPLITK == 1) {
        int do_relu = flags & 1, out_bf = flags & 2;
        #pragma unroll
        for (int mi = 0; mi < 2; ++mi) {
            #pragma unroll
            for (int ni = 0; ni < 2; ++ni) {
                int col = col0 + nw + ni * 16 + m16;
                float bval = bias[col];
                #pragma unroll
                for (int rr = 0; rr < 4; ++rr) {
                    int row = row0 + mw + mi * 16 + quad * 4 + rr;
                    float v = acc[mi][ni][rr] + bval;
                    if (do_relu) v = fmaxf(v, 0.0f);
                    if (out_bf) ((unsigned short*)out)[(size_t)row * Nfull + col] = f2bf(v);
                    else        ((float*)out)[(size_t)row * Nfull + col] = v;
                }
            }
        }
    } else {
        float* o = (float*)out;
        float bscale = (bz == 0) ? 1.0f : 0.0f;
        #pragma unroll
        for (int mi = 0; mi < 2; ++mi) {
            #pragma unroll
            for (int ni = 0; ni < 2; ++ni) {
                int col = col0 + nw + ni * 16 + m16;
                float bval = bias[col] * bscale;
                #pragma unroll
                for (int rr = 0; rr < 4; ++rr) {
                    int row = row0 + mw + mi * 16 + quad * 4 + rr;
                    atomicAdd(&o[(size_t)row * Nfull + col], acc[mi][ni][rr] + bval);
                }
            }
        }
    }
}

// ---------------------------------------------------------------- bf16 MFMA GEMM, 128x64-tile
// 4 waves, each 64x32 (4x2 frags). 2-phase dbuf, counted vmcnt(6).
__device__ __forceinline__ void stage12864(
    const unsigned short* __restrict__ Abase, const unsigned short* __restrict__ Bbase,
    int K, int k0, unsigned short* Asl, unsigned short* Bsl,
    int wave, int lane, int lr, int scol)
{
    #pragma unroll
    for (int p = 0; p < 4; ++p) {
        int chunk = wave * 4 + p;
        int r = chunk * 8 + lr;
        __builtin_amdgcn_global_load_lds(
            (const __attribute__((address_space(1))) unsigned int*)
                (Abase + (size_t)r * K + k0 + scol),
            (__attribute__((address_space(3))) unsigned int*)
                (Asl + chunk * 512 + lane * 8), 16, 0, 0);
    }
    #pragma unroll
    for (int p = 0; p < 2; ++p) {
        int chunk = wave * 2 + p;
        int r = chunk * 8 + lr;
        __builtin_amdgcn_global_load_lds(
            (const __attribute__((address_space(1))) unsigned int*)
                (Bbase + (size_t)r * K + k0 + scol),
            (__attribute__((address_space(3))) unsigned int*)
                (Bsl + chunk * 512 + lane * 8), 16, 0, 0);
    }
}

template<int SPLITK>
__global__ __launch_bounds__(256) void gemm128(
    const unsigned short* __restrict__ A, const unsigned short* __restrict__ Bt,
    const float* __restrict__ bias, void* __restrict__ out,
    int Nfull, int K, int flags, int P, int C)
{
    __shared__ __align__(16) unsigned short Asl[2][128 * 64];
    __shared__ __align__(16) unsigned short Bsl[2][64 * 64];
    int id = blockIdx.x;
    int xcd = id & 7, t = id >> 3, Gp = P >> 3;
    int by = xcd + 8 * (t % Gp);
    int r2 = t / Gp;
    int bx = r2 % C;
    int bz = r2 / C;
    int tid = threadIdx.x;
    int row0 = by * 128, col0 = bx * 64;
    if ((flags & 4) && col0 < 512 && row0 + 128 <= NORI) return;
    int kslice = K / SPLITK;
    int kbeg = bz * kslice;
    int nk = kslice >> 6;
    int wave = tid >> 6, lane = tid & 63;
    int quad = lane >> 4, m16 = lane & 15;
    int mw = (wave >> 1) * 64, nw = (wave & 1) * 32;
    int lr = lane >> 3;
    int scol = ((lane & 7) ^ lr) << 3;
    int rdswz = (m16 & 7) << 4;
    const unsigned short* Abase = A + (size_t)row0 * K;
    const unsigned short* Bbase = Bt + (size_t)col0 * K;
    floatx4 acc[4][2] = {};

    stage12864(Abase, Bbase, K, kbeg, Asl[0], Bsl[0], wave, lane, lr, scol);
    int cur = 0;
    for (int i = 0; i < nk; ++i) {
        if (i + 1 < nk) {
            stage12864(Abase, Bbase, K, kbeg + (i + 1) * 64,
                       Asl[cur ^ 1], Bsl[cur ^ 1], wave, lane, lr, scol);
            asm volatile("s_waitcnt vmcnt(6)" ::: "memory");
        } else {
            asm volatile("s_waitcnt vmcnt(0)" ::: "memory");
        }
        __builtin_amdgcn_s_barrier();
        const char* Ac = (const char*)Asl[cur];
        const char* Bc = (const char*)Bsl[cur];
        #pragma unroll
        for (int ks = 0; ks < 64; ks += 32) {
            short8 a[4], b[2];
            int cb = (ks + quad * 8) * 2;
            #pragma unroll
            for (int mi = 0; mi < 4; ++mi)
                a[mi] = *(const short8*)(Ac + (mw + mi * 16 + m16) * 128 + (cb ^ rdswz));
            #pragma unroll
            for (int ni = 0; ni < 2; ++ni)
                b[ni] = *(const short8*)(Bc + (nw + ni * 16 + m16) * 128 + (cb ^ rdswz));
            #pragma unroll
            for (int mi = 0; mi < 4; ++mi)
                #pragma unroll
                for (int ni = 0; ni < 2; ++ni)
                    acc[mi][ni] = __builtin_amdgcn_mfma_f32_16x16x32_bf16(
                        a[mi], b[ni], acc[mi][ni], 0, 0, 0);
        }
        __builtin_amdgcn_s_barrier();
        asm volatile("" ::: "memory");
        cur ^= 1;
    }
    if (SPLITK == 1) {
        int do_relu = flags & 1, out_bf = flags & 2;
        #pragma unroll
        for (int mi = 0; mi < 4; ++mi) {
            #pragma unroll
            for (int ni = 0; ni < 2; ++ni) {
                int col = col0 + nw + ni * 16 + m16;
                float bval = bias[col];
                #pragma unroll
                for (int rr = 0; rr < 4; ++rr) {
                    int row = row0 + mw + mi * 16 + quad * 4 + rr;
                    float v = acc[mi][ni][rr] + bval;
                    if (do_relu) v = fmaxf(v, 0.0f);
                    if (out_bf) ((unsigned short*)out)[(size_t)row * Nfull + col] = f2bf(v);
                    else        ((float*)out)[(size_t)row * Nfull + col] = v;
                }
            }
        }
    } else {
        float* o = (float*)out;
        float bscale = (bz == 0) ? 1.0f : 0.0f;
        #pragma unroll
        for (int mi = 0; mi < 4; ++mi) {
            #pragma unroll
            for (int ni = 0; ni < 2; ++ni) {
                int col = col0 + nw + ni * 16 + m16;
                float bval = bias[col] * bscale;
                #pragma unroll
                for (int rr = 0; rr < 4; ++rr) {
                    int row = row0 + mw + mi * 16 + quad * 4 + rr;
                    atomicAdd(&o[(size_t)row * Nfull + col], acc[mi][ni][rr] + bval);
                }
            }
        }
    }
}

// ---------------------------------------------------------------- block attention (layers 0..2)
__global__ __launch_bounds__(256) void attention(
    const unsigned short* __restrict__ qkv,  // [NT][1536] bf16, Q|K|V head-major
    const float* __restrict__ Bg,            // [NG][32][32]
    unsigned short* __restrict__ O)          // [NT][512] bf16 head-major
{
    int g = blockIdx.x >> 3;
    int hh = blockIdx.x & 7;
    __shared__ float Qs[32][65], Ks[32][65], Vs[32][65];
    __shared__ float S[32][33];
    int tid = threadIdx.x;
    int i = tid >> 3;
    int c0 = (tid & 7) * 8;
    int gn = (i < NP) ? g * NP + i : NORI + g;
    const unsigned short* base = qkv + (size_t)gn * 1536 + hh * DKH;
    short8 qv = *(const short8*)(base + c0);
    short8 kv = *(const short8*)(base + 512 + c0);
    short8 vv = *(const short8*)(base + 1024 + c0);
    #pragma unroll
    for (int j = 0; j < 8; ++j) {
        Qs[i][c0 + j] = bf2f((unsigned short)qv[j]);
        Ks[i][c0 + j] = bf2f((unsigned short)kv[j]);
        Vs[i][c0 + j] = bf2f((unsigned short)vv[j]);
    }
    __syncthreads();
    const float scale = 0.125f;
    #pragma unroll
    for (int e = 0; e < 4; ++e) {
        int idx = tid + e * 256;
        int si = idx >> 5, sj = idx & 31;
        float dot = 0.0f;
        #pragma unroll
        for (int k = 0; k < DKH; ++k) dot += Qs[si][k] * Ks[sj][k];
        S[si][sj] = dot * scale + Bg[(size_t)g * 1024 + si * 32 + sj];
    }
    __syncthreads();
    if (tid < 32) {
        float mx = -1e30f;
        #pragma unroll
        for (int j = 0; j < 32; ++j) mx = fmaxf(mx, S[tid][j]);
        float sum = 0.0f;
        #pragma unroll
        for (int j = 0; j < 32; ++j) { float e = __expf(S[tid][j] - mx); S[tid][j] = e; sum += e; }
        float inv = 1.0f / sum;
        #pragma unroll
        for (int j = 0; j < 32; ++j) S[tid][j] *= inv;
    }
    __syncthreads();
    short8 ov;
    #pragma unroll
    for (int cc = 0; cc < 8; ++cc) {
        float acc = 0.0f;
        #pragma unroll
        for (int j = 0; j < 32; ++j) acc += S[i][j] * Vs[j][c0 + cc];
        ov[cc] = (short)f2bf(acc);
    }
    *(short8*)(O + (size_t)gn * DIM + hh * DKH + c0) = ov;
}

// ---------------------------------------------------------------- last-layer attention
__global__ __launch_bounds__(64) void attention_last(
    const unsigned short* __restrict__ qkv, const float* __restrict__ Bg,
    unsigned short* __restrict__ O)
{
    int g = blockIdx.x >> 3, hh = blockIdx.x & 7;
    __shared__ float Ks[32][65], Vs[32][65];
    __shared__ float Qs[64], P[32];
    int tid = threadIdx.x;
    int j = tid & 31, hf = tid >> 5;
    int gn = (j < NP) ? g * NP + j : NORI + g;
    const unsigned short* kb = qkv + (size_t)gn * 1536 + hh * DKH + 512 + hf * 32;
    #pragma unroll
    for (int c = 0; c < 32; c += 8) {
        short8 k8 = *(const short8*)(kb + c);
        short8 v8 = *(const short8*)(kb + 512 + c);
        #pragma unroll
        for (int t = 0; t < 8; ++t) {
            Ks[j][hf * 32 + c + t] = bf2f((unsigned short)k8[t]);
            Vs[j][hf * 32 + c + t] = bf2f((unsigned short)v8[t]);
        }
    }
    Qs[tid] = bf2f(qkv[(size_t)(NORI + g) * 1536 + hh * DKH + tid]);
    __syncthreads();
    float s;
    if (tid < 32) {
        float dot = 0.0f;
        #pragma unroll
        for (int k = 0; k < 64; ++k) dot += Qs[k] * Ks[tid][k];
        s = dot * 0.125f + Bg[(size_t)g * 1024 + 31 * 32 + tid];
    } else s = -1e30f;
    float mx = s;
    #pragma unroll
    for (int off = 32; off > 0; off >>= 1) mx = fmaxf(mx, __shfl_xor(mx, off));
    float e = (tid < 32) ? __expf(s - mx) : 0.0f;
    float sum = e;
    #pragma unroll
    for (int off = 32; off > 0; off >>= 1) sum += __shfl_xor(sum, off);
    if (tid < 32) P[tid] = e / sum;
    __syncthreads();
    float acc = 0.0f;
    #pragma unroll
    for (int jj = 0; jj < 32; ++jj) acc += P[jj] * Vs[jj][tid];
    O[(size_t)(NORI + g) * DIM + hh * DKH + tid] = f2bf(acc);
}

// ---------------------------------------------------------------- launch
extern "C" void kernel_launch(void* const* d_in, const int* in_sizes, int n_in,
                              void* d_out, int out_size, void* d_ws, size_t ws_size,
                              hipStream_t stream)
{
    const float* x        = (const float*)d_in[0];
    const int*   sp       = (const int*)d_in[1];
    const int*   degrees  = (const int*)d_in[3];
    const float* init_W   = (const float*)d_in[4];
    const float* init_b   = (const float*)d_in[5];
    const float* cent_emb = (const float*)d_in[6];
    const float* db       = (const float*)d_in[7];
    const float* vbias    = (const float*)d_in[8];
    const float* Wq       = (const float*)d_in[9];
    const float* bq       = (const float*)d_in[10];
    const float* Wk       = (const float*)d_in[11];
    const float* bk       = (const float*)d_in[12];
    const float* Wv       = (const float*)d_in[13];
    const float* bv       = (const float*)d_in[14];
    const float* Wo       = (const float*)d_in[15];
    const float* bo       = (const float*)d_in[16];
    const float* W1       = (const float*)d_in[17];
    const float* b1       = (const float*)d_in[18];
    const float* W2       = (const float*)d_in[19];
    const float* b2       = (const float*)d_in[20];

    char* ws = (char*)d_ws;
    float*          h      = (float*)ws;          ws += (size_t)NT * DIM * 4;
    unsigned short* hn     = (unsigned short*)ws; ws += (size_t)NT * DIM * 2;
    unsigned short* o      = (unsigned short*)ws; ws += (size_t)NT * DIM * 2;
    unsigned short* qkv    = (unsigned short*)ws; ws += (size_t)NT * FFD * 2;      // aliased qkv/ffn
    float*          Bg     = (float*)ws;          ws += (size_t)NG * 1024 * 4;
    unsigned short* Wqkv_t = (unsigned short*)ws; ws += (size_t)NLAY * 1536 * DIM * 2;
    unsigned short* Wo_t   = (unsigned short*)ws; ws += (size_t)NLAY * DIM * DIM * 2;
    unsigned short* W1_t   = (unsigned short*)ws; ws += (size_t)NLAY * FFD * DIM * 2;
    unsigned short* W2_t   = (unsigned short*)ws; ws += (size_t)NLAY * DIM * FFD * 2;
    float*          bqkv   = (float*)ws;          ws += (size_t)NLAY * 1536 * 4;
    unsigned short* ffnb   = qkv;

    // prep (1 launch)
    prep_all<<<14424, 256, 0, stream>>>(
        x, degrees, init_W, init_b, cent_emb, h, sp, db, vbias, Bg,
        Wq, Wk, Wv, bq, bk, bv, Wqkv_t, bqkv, Wo, W1, W2, Wo_t, W1_t, W2_t);

    for (int l = 0; l < NLAY - 1; ++l) {
        layernorm_bf16<<<NT, 256, 0, stream>>>(h, hn, 0, nullptr);
        gemm64g<1><<<32 * 24, 256, 0, stream>>>(
            hn, Wqkv_t + (size_t)l * 1536 * DIM, bqkv + (size_t)l * 1536,
            qkv, 1536, DIM, /*bf16 out*/2, 32, 24);
        attention<<<NG * NHD, 256, 0, stream>>>(qkv, Bg, o);
        gemm128<4><<<16 * 8 * 4, 256, 0, stream>>>(
            o, Wo_t + (size_t)l * DIM * DIM, bo + (size_t)l * DIM,
            h, DIM, DIM, 0, 16, 8);
        layernorm_bf16<<<NT, 256, 0, stream>>>(h, hn, 0, nullptr);
        gemm64g<1><<<32 * 32, 256, 0, stream>>>(
            hn, W1_t + (size_t)l * FFD * DIM, b1 + (size_t)l * FFD,
            ffnb, FFD, DIM, /*relu+bf16*/3, 32, 32);
        gemm128<4><<<16 * 8 * 4, 256, 0, stream>>>(
            ffnb, W2_t + (size_t)l * DIM * FFD, b2 + (size_t)l * DIM,
            h, DIM, FFD, 0, 16, 8);
    }

    // ---- last layer: only virtual rows reach the output ----
    {
        int l = NLAY - 1;
        layernorm_bf16<<<NT, 256, 0, stream>>>(h, hn, 0, nullptr);
        // K,V for all rows; Q only for the panel containing virtual rows (flag 4)
        gemm64g<1><<<32 * 24, 256, 0, stream>>>(
            hn, Wqkv_t + (size_t)l * 1536 * DIM, bqkv + (size_t)l * 1536,
            qkv, 1536, DIM, /*bf16 out + lastQKV*/6, 32, 24);
        attention_last<<<NG * NHD, 64, 0, stream>>>(qkv, Bg, o);
        gemm64<8><<<1 * 8 * 8, 256, 0, stream>>>(
            o, Wo_t + (size_t)l * DIM * DIM, bo + (size_t)l * DIM,
            h, DIM, DIM, NORI, 0, 1, 8, 0);
        // LN over virtual rows; seed d_out with the fp32 residual rows
        layernorm_bf16<<<NG, 256, 0, stream>>>(h, hn, NORI, (float*)d_out);
        gemm64<1><<<1 * 32, 256, 0, stream>>>(
            hn, W1_t + (size_t)l * FFD * DIM, b1 + (size_t)l * FFD,
            ffnb, FFD, DIM, NORI, 3, 1, 32, 0);
        // FFN2 accumulates directly into d_out (residual already there)
        gemm64<8><<<1 * 8 * 8, 256, 0, stream>>>(
            ffnb, W2_t + (size_t)l * DIM * FFD, b2 + (size_t)l * DIM,
            d_out, DIM, FFD, NORI, 0, 1, 8, NORI);
    }
}